// Round 2
// baseline (419.403 us; speedup 1.0000x reference)
//
#include <hip/hip_runtime.h>
#include <hip/hip_bf16.h>
#include <stdint.h>

typedef __attribute__((ext_vector_type(8))) short short8;
typedef __attribute__((ext_vector_type(4))) float floatx4;
typedef __attribute__((ext_vector_type(2))) unsigned int uint2v;

#define DEV static __device__ __forceinline__

DEV unsigned short f2bs(float f) {           // f32 -> bf16 bits, RNE
  union { float f; unsigned u; } v; v.f = f;
  unsigned u = v.u;
  u += 0x7fffu + ((u >> 16) & 1u);
  return (unsigned short)(u >> 16);
}
DEV float bs2f(unsigned short s) {
  union { unsigned u; float f; } v; v.u = ((unsigned)s) << 16;
  return v.f;
}
DEV unsigned pack2(float a, float b) {
  return (unsigned)f2bs(a) | ((unsigned)f2bs(b) << 16);
}

DEV void gload_lds16(const void* g, void* l) {
  __builtin_amdgcn_global_load_lds(
      (const __attribute__((address_space(1))) void*)g,
      (__attribute__((address_space(3))) void*)l, 16, 0, 0);
}

static constexpr int Hdim = 1024;
static constexpr int KDim = 512;
static constexpr int NH = 16;
static constexpr int HK = 32;
static constexpr int HV = 64;
static constexpr int Ttok = 8192;
static constexpr int Mtok = 4 * 8192;

// ---------- f32 -> bf16 convert (weights) ----------
__global__ __launch_bounds__(256) void k_cvt(const float4* __restrict__ in,
                                             uint2v* __restrict__ out, int n4) {
  int i = blockIdx.x * 256 + threadIdx.x;
  if (i >= n4) return;
  float4 v = in[i];
  uint2v o;
  o.x = pack2(v.x, v.y);
  o.y = pack2(v.z, v.w);
  out[i] = o;
}

// ---------- rmsnorm(hidden) -> X bf16 ----------
__global__ __launch_bounds__(256) void k_rmsnorm(const float* __restrict__ hs,
                                                 const float* __restrict__ nw,
                                                 uint2v* __restrict__ X) {
  const int token = blockIdx.x;
  const int tid = threadIdx.x;
  float4 h = ((const float4*)(hs + (size_t)token * Hdim))[tid];
  float ss = h.x * h.x + h.y * h.y + h.z * h.z + h.w * h.w;
#pragma unroll
  for (int off = 32; off > 0; off >>= 1) ss += __shfl_down(ss, off, 64);
  __shared__ float red[4];
  const int lane = tid & 63, wid = tid >> 6;
  if (lane == 0) red[wid] = ss;
  __syncthreads();
  float tot = red[0] + red[1] + red[2] + red[3];
  float sc = rsqrtf(tot * (1.0f / Hdim) + 1e-5f);
  float4 w = ((const float4*)nw)[tid];
  uint2v o;
  o.x = pack2(h.x * sc * w.x, h.y * sc * w.y);
  o.y = pack2(h.z * sc * w.z, h.w * sc * w.w);
  X[(size_t)token * 256 + tid] = o;
}

// ---------- bf16 GEMM, B^T layout: C[M,N] = A[M,K] * W[N,K]^T ----------
// EPI 0: store f32      EPI 1: store bf16(sigmoid(acc))
// EPI 2: store f32(gate[m,n] * acc) to output (d_out is float32)
template <int EPI>
__global__ __launch_bounds__(256, 2) void k_gemm_bt(
    const unsigned short* __restrict__ A, const unsigned short* __restrict__ Bw,
    void* __restrict__ Cout, const unsigned short* __restrict__ Gate,
    const int N, const int K) {
  __shared__ unsigned short As[128 * 64];
  __shared__ unsigned short Bs[128 * 64];
  const int tid = threadIdx.x;
  const int lane = tid & 63;
  const int w = tid >> 6;
  const int wr = w >> 1, wc = w & 1;
  const int m0 = blockIdx.y * 128;
  const int n0 = blockIdx.x * 128;

  floatx4 acc[4][4];
#pragma unroll
  for (int i = 0; i < 4; ++i)
#pragma unroll
    for (int j = 0; j < 4; ++j) acc[i][j] = (floatx4){0.f, 0.f, 0.f, 0.f};

  // staging coords: thread tid loads 16B of [128][64] bf16 tile
  const int r_a = tid >> 3;          // row within 32-row chunk
  const int c_a = (tid & 7) * 8;     // col in shorts
  const unsigned short* Ag = A + (size_t)(m0 + r_a) * K + c_a;
  const unsigned short* Bg = Bw + (size_t)(n0 + r_a) * K + c_a;
  char* AsDst = (char*)As + tid * 16;
  char* BsDst = (char*)Bs + tid * 16;

  const int fr_row = lane & 15;      // fragment row/col within 16
  const int fr_k = (lane >> 4) * 8;  // k sub-offset

  for (int k0 = 0; k0 < K; k0 += 64) {
#pragma unroll
    for (int i = 0; i < 4; ++i)
      gload_lds16(Ag + (size_t)i * 32 * K + k0, AsDst + i * 4096);
#pragma unroll
    for (int i = 0; i < 4; ++i)
      gload_lds16(Bg + (size_t)i * 32 * K + k0, BsDst + i * 4096);
    __syncthreads();
#pragma unroll
    for (int kk = 0; kk < 64; kk += 32) {
      short8 a[4], b[4];
#pragma unroll
      for (int mi = 0; mi < 4; ++mi)
        a[mi] = *(const short8*)&As[(wr * 64 + mi * 16 + fr_row) * 64 + kk + fr_k];
#pragma unroll
      for (int ni = 0; ni < 4; ++ni)
        b[ni] = *(const short8*)&Bs[(wc * 64 + ni * 16 + fr_row) * 64 + kk + fr_k];
#pragma unroll
      for (int mi = 0; mi < 4; ++mi)
#pragma unroll
        for (int ni = 0; ni < 4; ++ni)
          acc[mi][ni] = __builtin_amdgcn_mfma_f32_16x16x32_bf16(
              a[mi], b[ni], acc[mi][ni], 0, 0, 0);
    }
    __syncthreads();
  }

  // epilogue: C/D layout col = lane&15, row = (lane>>4)*4 + r
  const int rb = (lane >> 4) * 4;
#pragma unroll
  for (int mi = 0; mi < 4; ++mi)
#pragma unroll
    for (int ni = 0; ni < 4; ++ni) {
      const floatx4 v = acc[mi][ni];
      const int n = n0 + wc * 64 + ni * 16 + (lane & 15);
#pragma unroll
      for (int r = 0; r < 4; ++r) {
        const int m = m0 + wr * 64 + mi * 16 + rb + r;
        const size_t idx = (size_t)m * N + n;
        if (EPI == 0) {
          ((float*)Cout)[idx] = v[r];
        } else if (EPI == 1) {
          float s = 1.0f / (1.0f + __expf(-v[r]));
          ((unsigned short*)Cout)[idx] = f2bs(s);
        } else {
          float g = bs2f(Gate[idx]);
          ((float*)Cout)[idx] = g * v[r];   // d_out is float32
        }
      }
    }
}

// ---------- q-normalize (folded) + state contraction + head rmsnorm ----------
__global__ __launch_bounds__(256) void k_qstate(const float* __restrict__ Q,
                                                const float* __restrict__ S,
                                                const float* __restrict__ vnw,
                                                unsigned short* __restrict__ O) {
  __shared__ float Sl[HK * HV];  // 8 KB, one head's state
  __shared__ float Vl[HV];
  const int tid = threadIdx.x;
  const int h = blockIdx.y;
  const int tt0 = blockIdx.x * 256;
  const int b = tt0 / Ttok;
  const float* Sp = S + (size_t)(b * NH + h) * (HK * HV);
#pragma unroll
  for (int i = 0; i < 2; ++i)
    ((float4*)Sl)[tid + i * 256] = ((const float4*)Sp)[tid + i * 256];
  if (tid < HV) Vl[tid] = vnw[tid];
  __syncthreads();

  const int tt = tt0 + tid;
  const float* qp = Q + (size_t)tt * KDim + h * HK;
  float q[HK];
#pragma unroll
  for (int i = 0; i < 8; ++i) {
    float4 v = ((const float4*)qp)[i];
    q[4 * i] = v.x; q[4 * i + 1] = v.y; q[4 * i + 2] = v.z; q[4 * i + 3] = v.w;
  }
  float ss = 0.f;
#pragma unroll
  for (int k = 0; k < HK; ++k) ss += q[k] * q[k];
  const float inv = 1.0f / fmaxf(sqrtf(ss), 1e-12f);  // fold normalize into o

  float4 o[16];
#pragma unroll
  for (int v = 0; v < 16; ++v) o[v] = (float4){0.f, 0.f, 0.f, 0.f};
#pragma unroll 4
  for (int k = 0; k < HK; ++k) {
    const float qk = q[k];
    const float4* sr = (const float4*)&Sl[k * HV];
#pragma unroll
    for (int v = 0; v < 16; ++v) {
      float4 s = sr[v];
      o[v].x += qk * s.x; o[v].y += qk * s.y;
      o[v].z += qk * s.z; o[v].w += qk * s.w;
    }
  }
  float ss2 = 0.f;
#pragma unroll
  for (int v = 0; v < 16; ++v) {
    o[v].x *= inv; o[v].y *= inv; o[v].z *= inv; o[v].w *= inv;
    ss2 += o[v].x * o[v].x + o[v].y * o[v].y + o[v].z * o[v].z + o[v].w * o[v].w;
  }
  const float sc = rsqrtf(ss2 * (1.0f / HV) + 1e-5f);
  unsigned short* Op = O + (size_t)tt * Hdim + h * HV;
#pragma unroll
  for (int v = 0; v < 16; ++v) {
    float4 wv = ((const float4*)Vl)[v];
    uint2v ov;
    ov.x = pack2(o[v].x * sc * wv.x, o[v].y * sc * wv.y);
    ov.y = pack2(o[v].z * sc * wv.z, o[v].w * sc * wv.w);
    ((uint2v*)Op)[v] = ov;
  }
}

extern "C" void kernel_launch(void* const* d_in, const int* in_sizes, int n_in,
                              void* d_out, int out_size, void* d_ws, size_t ws_size,
                              hipStream_t stream) {
  const float* hs = (const float*)d_in[0];
  const float* Srec = (const float*)d_in[1];
  const float* nw = (const float*)d_in[2];
  const float* qw = (const float*)d_in[3];
  const float* vnw = (const float*)d_in[4];
  const float* ow = (const float*)d_in[5];
  const float* gw = (const float*)d_in[6];

  char* ws = (char*)d_ws;
  unsigned short* X = (unsigned short*)(ws);                          // 64 MB bf16 [M,H]
  unsigned short* Ob = (unsigned short*)(ws + ((size_t)64 << 20));    // 64 MB bf16 [M,VD]
  unsigned short* Gs = (unsigned short*)(ws + ((size_t)128 << 20));   // 64 MB bf16 [M,H]
  float* Qf = (float*)(ws + ((size_t)192 << 20));                     // 64 MB f32 [M,KD]
  unsigned short* qwb = (unsigned short*)(ws + ((size_t)256 << 20));  // 1 MB
  unsigned short* gwb = (unsigned short*)(ws + ((size_t)257 << 20));  // 2 MB
  unsigned short* owb = (unsigned short*)(ws + ((size_t)259 << 20));  // 2 MB

  // weights f32 -> bf16
  k_cvt<<<(KDim * Hdim / 4 + 255) / 256, 256, 0, stream>>>(
      (const float4*)qw, (uint2v*)qwb, KDim * Hdim / 4);
  k_cvt<<<(Hdim * Hdim / 4 + 255) / 256, 256, 0, stream>>>(
      (const float4*)gw, (uint2v*)gwb, Hdim * Hdim / 4);
  k_cvt<<<(Hdim * Hdim / 4 + 255) / 256, 256, 0, stream>>>(
      (const float4*)ow, (uint2v*)owb, Hdim * Hdim / 4);

  // x = rmsnorm(hidden) -> bf16
  k_rmsnorm<<<Mtok, 256, 0, stream>>>(hs, nw, (uint2v*)X);

  // Q = X @ q_w^T  (f32 out)
  k_gemm_bt<0><<<dim3(KDim / 128, Mtok / 128), 256, 0, stream>>>(
      X, qwb, Qf, nullptr, KDim, Hdim);

  // per-head: normalize-fold + state contraction + rmsnorm -> Ob bf16
  k_qstate<<<dim3(Mtok / 256, NH), 256, 0, stream>>>(Qf, Srec, vnw, Ob);

  // Gs = sigmoid(X @ gate_w^T) -> bf16
  k_gemm_bt<1><<<dim3(Hdim / 128, Mtok / 128), 256, 0, stream>>>(
      X, gwb, Gs, nullptr, Hdim, Hdim);

  // out = Gs * (Ob @ o_w^T) -> f32 d_out
  k_gemm_bt<2><<<dim3(Hdim / 128, Mtok / 128), 256, 0, stream>>>(
      Ob, owb, (float*)d_out, Gs, Hdim, Hdim);
}